// Round 4
// baseline (341.310 us; speedup 1.0000x reference)
//
#include <hip/hip_runtime.h>
#include <cstdint>

#define GRIDW   40
#define SEQ     1600      // 40*40
#define NVOCAB  32
#define PATH_ID 6
#define IGNORE_ID (-100)
#define NWORDS  25        // 1600 / 64
#define BLK     512
#define NWAVES  (BLK / 64)

typedef float f32x4 __attribute__((ext_vector_type(4)));

// ---------------------------------------------------------------------------
// One block per batch row, 512 threads (8 waves), 32 waves/CU
// (__launch_bounds__(512,8) keeps VGPR<=64 -- round-3 validated, -4.4us).
// Round-4 change: logits/labels loads are NONTEMPORAL (global_load ... nt,
// no L2/L3 allocate). Theory: the 800-MiB harness poison fill that precedes
// the kernel in the timed graph leaves the 256-MiB L3 full of dirty lines;
// ordinary reads allocate and evict ~210 MB of dirty data -> writebacks on
// our critical path ((210 rd + 210 wb)/54us ~= HBM peak, matching rounds
// 0-3 exactly). Streaming reads skip the allocation, dropping the inherited
// writeback traffic. Data is read exactly once, so nt costs nothing.
// Phase 1: single-pass online log-sum-exp + argmax, fused ballot word-pack.
// Phase 2: wave-scan prefix, spatial penalty, min-label connected
// components, one atomicAdd per row.
// ---------------------------------------------------------------------------
__global__ __launch_bounds__(BLK, 8) void act_loss_kernel(
    const float* __restrict__ logits,   // [B, SEQ, NVOCAB]
    const int*   __restrict__ labels,   // [B, SEQ]
    const float* __restrict__ qhalt,    // [B]
    float*       __restrict__ out,      // [1]
    int B)
{
    const int b    = blockIdx.x;
    const int tid  = threadIdx.x;
    const int lane = tid & 63;
    const int wid  = tid >> 6;

    __shared__ uint8_t  path[SEQ];
    __shared__ uint16_t lab[SEQ];
    __shared__ uint16_t pos[SEQ];
    __shared__ uint64_t words[NWORDS];
    __shared__ int      offs[NWORDS + 1];
    __shared__ int      npath_s;
    __shared__ float    wr_f[NWAVES];
    __shared__ int      wr_i[NWAVES];
    __shared__ int      wr_j[NWAVES];
    __shared__ float    part_a;   // lm + 0.5*bce for this row

    // ---------------- Phase 1: online CE / argmax, fused word pack ----------
    float ce_sum = 0.0f;
    int   cnt = 0, cor = 0;

    const float* base  = logits + (size_t)b * SEQ * NVOCAB;
    const int*   lbase = labels + (size_t)b * SEQ;

    // online update over one chunk of 8 logits held in two f32x4s.
    // first chunk (b0==0) initializes; later chunks rescale s on new max.
    // strict > everywhere => first-occurrence argmax preserved.
#define CH(qa, qb, b0)                                                      \
    {                                                                       \
        float cm = qa.x; int ca = (b0);                                     \
        if (qa.y > cm) { cm = qa.y; ca = (b0) + 1; }                        \
        if (qa.z > cm) { cm = qa.z; ca = (b0) + 2; }                        \
        if (qa.w > cm) { cm = qa.w; ca = (b0) + 3; }                        \
        if (qb.x > cm) { cm = qb.x; ca = (b0) + 4; }                        \
        if (qb.y > cm) { cm = qb.y; ca = (b0) + 5; }                        \
        if (qb.z > cm) { cm = qb.z; ca = (b0) + 6; }                        \
        if (qb.w > cm) { cm = qb.w; ca = (b0) + 7; }                        \
        if ((b0) == 0) { m = cm; arg = ca; }                                \
        else if (cm > m) { s *= __expf(m - cm); m = cm; arg = ca; }         \
        s += __expf(qa.x - m) + __expf(qa.y - m)                            \
           + __expf(qa.z - m) + __expf(qa.w - m)                            \
           + __expf(qb.x - m) + __expf(qb.y - m)                            \
           + __expf(qb.z - m) + __expf(qb.w - m);                           \
        if ((slbl >> 3) == ((b0) >> 3)) {                                   \
            int k = slbl & 7;                                               \
            xl = (k == 0) ? qa.x : (k == 1) ? qa.y : (k == 2) ? qa.z :      \
                 (k == 3) ? qa.w : (k == 4) ? qb.x : (k == 5) ? qb.y :      \
                 (k == 6) ? qb.z : qb.w;                                    \
        }                                                                   \
    }

#pragma unroll 1
    for (int i = tid; i < SEQ; i += BLK) {
        const f32x4* p4 = (const f32x4*)(base + (size_t)i * NVOCAB);
        f32x4 q0 = __builtin_nontemporal_load(p4 + 0);
        f32x4 q1 = __builtin_nontemporal_load(p4 + 1);
        f32x4 q2 = __builtin_nontemporal_load(p4 + 2);
        f32x4 q3 = __builtin_nontemporal_load(p4 + 3);
        f32x4 q4 = __builtin_nontemporal_load(p4 + 4);
        f32x4 q5 = __builtin_nontemporal_load(p4 + 5);
        f32x4 q6 = __builtin_nontemporal_load(p4 + 6);
        f32x4 q7 = __builtin_nontemporal_load(p4 + 7);
        int lbl  = __builtin_nontemporal_load(lbase + i);
        int slbl = (lbl < 0) ? 0 : lbl;

        float m, xl = 0.0f, s = 0.0f;
        int   arg;
        CH(q0, q1, 0)
        CH(q2, q3, 8)
        CH(q4, q5, 16)
        CH(q6, q7, 24)

        bool msk = (lbl != IGNORE_ID);
        float lse = m + __logf(s);
        ce_sum += msk ? (lse - xl) : 0.0f;
        cnt    += msk ? 1 : 0;
        cor    += (msk && arg == lbl) ? 1 : 0;

        bool pf = (arg == PATH_ID);
        path[i] = pf ? 1 : 0;
        uint64_t w = __ballot(pf);
        if (lane == 0) words[i >> 6] = w;   // i = it*BLK + wid*64 for lane 0
    }
#undef CH
    __syncthreads();   // path[], words[] complete

    // ---------------- block reductions: ce_sum, cnt, cor (shfl trees) -------
    for (int d = 1; d < 64; d <<= 1) {
        ce_sum += __shfl_xor(ce_sum, d);
        cnt    += __shfl_xor(cnt, d);
        cor    += __shfl_xor(cor, d);
    }
    if (lane == 0) { wr_f[wid] = ce_sum; wr_i[wid] = cnt; wr_j[wid] = cor; }
    __syncthreads();   // wave partials visible

    if (tid == 0) {
        float ce_tot = 0.0f; int c_tot = 0, k_tot = 0;
#pragma unroll
        for (int v = 0; v < NWAVES; ++v) {
            ce_tot += wr_f[v]; c_tot += wr_i[v]; k_tot += wr_j[v];
        }
        float lm = ce_tot / (float)max(c_tot, 1);
        float t  = (k_tot == c_tot) ? 1.0f : 0.0f;
        float xq = qhalt[b];
        float bce = fmaxf(xq, 0.0f) - xq * t + log1pf(expf(-fabsf(xq)));
        part_a = lm + 0.5f * bce;
    }

    // ---------------- offs prefix: wave-0 scan over 25 word popcounts -------
    if (wid == 0) {
        uint64_t w = (lane < NWORDS) ? words[lane] : 0ull;
        int pc = __popcll(w);
        int c = pc;
        for (int d = 1; d < 32; d <<= 1) {
            int t = __shfl_up(c, d);
            if (lane >= d) c += t;
        }
        if (lane < NWORDS) offs[lane] = c - pc;          // exclusive prefix
        if (lane == NWORDS - 1) { offs[NWORDS] = c; npath_s = c; }
    }
    __syncthreads();   // offs/npath_s/part_a visible

    // ---------------- scatter path positions + init labels ------------------
    for (int i = tid; i < SEQ; i += BLK)
        lab[i] = path[i] ? (uint16_t)i : (uint16_t)0xFFFF;
    if (tid < NWORDS) {
        int o = offs[tid];
        uint64_t w = words[tid];
        int basei = tid * 64;
        while (w) {
            int k = __ffsll((unsigned long long)w) - 1;
            pos[o++] = (uint16_t)(basei + k);
            w &= (w - 1);
        }
    }
    __syncthreads();

    // ---------------- spatial penalty ---------------------------------------
    const int np = npath_s;
    int sp_units = 0;
    for (int q = tid; q + 1 < np; q += BLK) {
        int i = pos[q], j = pos[q + 1];
        int dist = abs(i / GRIDW - j / GRIDW) + abs(i % GRIDW - j % GRIDW);
        if (dist > 1) sp_units += dist - 1;
    }

    // ---------------- connectivity: min-label propagation -------------------
    for (;;) {
        int local = 0;
        for (int i = tid; i < SEQ; i += BLK) {
            if (!path[i]) continue;
            int r = i / GRIDW, c = i % GRIDW;
            uint16_t v = lab[i];
            uint16_t nm = v;
            if (r > 0)         { uint16_t u = lab[i - GRIDW]; nm = (u < nm) ? u : nm; }
            if (r < GRIDW - 1) { uint16_t u = lab[i + GRIDW]; nm = (u < nm) ? u : nm; }
            if (c > 0)         { uint16_t u = lab[i - 1];     nm = (u < nm) ? u : nm; }
            if (c < GRIDW - 1) { uint16_t u = lab[i + 1];     nm = (u < nm) ? u : nm; }
            if (nm < v) { lab[i] = nm; local = 1; }
        }
        if (__syncthreads_count(local) == 0) break;
    }

    int comp = 0;
    for (int i = tid; i < SEQ; i += BLK)
        comp += (path[i] && lab[i] == (uint16_t)i) ? 1 : 0;

    // ---------------- reduce sp_units / comp, emit row contribution ---------
    for (int d = 1; d < 64; d <<= 1) {
        sp_units += __shfl_xor(sp_units, d);
        comp     += __shfl_xor(comp, d);
    }
    if (lane == 0) { wr_i[wid] = sp_units; wr_j[wid] = comp; }
    __syncthreads();

    if (tid == 0) {
        int sp_tot = 0, comp_tot = 0;
#pragma unroll
        for (int v = 0; v < NWAVES; ++v) { sp_tot += wr_i[v]; comp_tot += wr_j[v]; }
        int conn_units = (comp_tot > 1) ? (comp_tot - 1) : 0;
        float total = part_a +
                      ((float)sp_tot * 10.0f + (float)conn_units * 5.0f) / (float)B;
        atomicAdd(out, total);
    }
}

extern "C" void kernel_launch(void* const* d_in, const int* in_sizes, int n_in,
                              void* d_out, int out_size, void* d_ws, size_t ws_size,
                              hipStream_t stream) {
    const float* logits = (const float*)d_in[0];
    const int*   labels = (const int*)d_in[1];
    const float* qhalt  = (const float*)d_in[2];
    // d_in[3] = halted, d_in[4] = steps: metrics-only in reference, unused.
    float* out = (float*)d_out;
    const int B = in_sizes[2];   // q_halt_logits length = batch

    // harness poisons d_out before every launch; we accumulate via atomicAdd,
    // so zero it on-stream first (graph-capture safe).
    hipMemsetAsync(out, 0, (size_t)out_size * sizeof(float), stream);
    act_loss_kernel<<<dim3(B), dim3(BLK), 0, stream>>>(logits, labels, qhalt, out, B);
}

// Round 6
// 284.836 us; speedup vs baseline: 1.1983x; 1.1983x over previous
//
#include <hip/hip_runtime.h>
#include <cstdint>

#define GRIDW   40
#define SEQ     1600      // 40*40
#define NVOCAB  32
#define PATH_ID 6
#define IGNORE_ID (-100)
#define NWORDS  25        // 1600 / 64
#define BLK     512
#define NWAVES  (BLK / 64)
#define ROWS_PER_BLK 2

typedef float f32x4 __attribute__((ext_vector_type(4)));

// ---------------------------------------------------------------------------
// (Resubmission of round-5 experiment: container infra failed twice; kernel
// re-audited -- LDS 74KB/block legal on gfx950, barriers uniform, swizzle
// algebra verified. No GPU-side fault path found.)
//
// 512 blocks x 512 threads; each block processes 2 CONSECUTIVE batch rows
// sequentially (512 long streams instead of 1024 short ones -> DRAM page
// locality). Phase 1 per row: each wave stages a 64-token tile with 8 fully
// coalesced NONTEMPORAL 1-KiB loads (every cache line covered by exactly one
// instruction, so no-allocate costs nothing -- unlike round 4's strided nt,
// which 8x'd request traffic). nt reads skip L2/L3 allocation, so they stop
// evicting the ~200 MB of dirty poison-fill lines the preceding 800-MiB fill
// leaves in the 256-MiB L3 (writebacks that otherwise land on our critical
// path: (216 rd + 200 wb)/6.3 TB/s ~= the observed ~60 us kernel slice).
// Stage layout is XOR-swizzled (slot = tok*8 + (comp ^ (tok&7))): 8-way
// bank-group balanced on both ds_write_b128 and ds_read_b128, no padding,
// 8 KB/wave. LDS ~74 KB/block -> 2 blocks/CU (16 waves/CU).
// Phase 2 per row: ballot words, wave-scan prefix, spatial penalty,
// min-label connected components, one atomicAdd per row.
// ---------------------------------------------------------------------------
__global__ __launch_bounds__(BLK, 4) void act_loss_kernel(
    const float* __restrict__ logits,   // [B, SEQ, NVOCAB]
    const int*   __restrict__ labels,   // [B, SEQ]
    const float* __restrict__ qhalt,    // [B]
    float*       __restrict__ out,      // [1]
    int B)
{
    const int tid  = threadIdx.x;
    const int lane = tid & 63;
    const int wid  = tid >> 6;

    __shared__ __align__(16) f32x4 stage[NWAVES * 512];  // 64 KiB, wave-private 8 KiB each
    __shared__ uint8_t  path[SEQ];
    __shared__ uint16_t lab[SEQ];
    __shared__ uint16_t pos[SEQ];
    __shared__ uint64_t words[NWORDS];
    __shared__ int      offs[NWORDS + 1];
    __shared__ int      npath_s;
    __shared__ float    wr_f[NWAVES];
    __shared__ int      wr_i[NWAVES];
    __shared__ int      wr_j[NWAVES];
    __shared__ float    part_a;   // lm + 0.5*bce for current row

    f32x4* stg = stage + wid * 512;            // this wave's stage region
    const float* stf = (const float*)stg;

    for (int r = 0; r < ROWS_PER_BLK; ++r) {
        const int b = blockIdx.x * ROWS_PER_BLK + r;
        if (b >= B) break;

        const f32x4* gbase = (const f32x4*)(logits + (size_t)b * SEQ * NVOCAB);
        const int*   lbase = labels + (size_t)b * SEQ;

        // ---------------- Phase 1: per-token CE / argmax --------------------
        float ce_sum = 0.0f;
        int   cnt = 0, cor = 0;

#pragma unroll 1
        for (int tile = wid; tile < SEQ / 64; tile += NWAVES) {   // 25 tiles
            const f32x4* gp = gbase + (size_t)tile * 512;         // 64 tok * 8 f4

            // 8 coalesced 1-KiB nontemporal loads (full-line coverage per instr)
            f32x4 g[8];
#pragma unroll
            for (int k = 0; k < 8; ++k)
                g[k] = __builtin_nontemporal_load(gp + k * 64 + lane);

            int tok = tile * 64 + lane;
            int lbl = __builtin_nontemporal_load(lbase + tok);

            // transpose into XOR-swizzled LDS: slot = tok8*8 + (comp ^ (tok8&7))
#pragma unroll
            for (int k = 0; k < 8; ++k) {
                int t8  = k * 8 + (lane >> 3);     // token within tile
                int cmp = lane & 7;                // f4 component
                stg[t8 * 8 + (cmp ^ (t8 & 7))] = g[k];
            }
            // read back own token (token-in-tile == lane); same-wave RAW,
            // compiler inserts lgkmcnt -- no barrier needed (wave-private).
            f32x4 x[8];
#pragma unroll
            for (int j = 0; j < 8; ++j)
                x[j] = stg[lane * 8 + (j ^ (lane & 7))];

            // argmax, first occurrence (ascending, strict >)
            float m = x[0].x; int arg = 0;
#pragma unroll
            for (int j = 0; j < 8; ++j) {
                int i4 = 4 * j;
                if (j > 0 && x[j].x > m) { m = x[j].x; arg = i4; }
                if (x[j].y > m) { m = x[j].y; arg = i4 + 1; }
                if (x[j].z > m) { m = x[j].z; arg = i4 + 2; }
                if (x[j].w > m) { m = x[j].w; arg = i4 + 3; }
            }
            // sum exp(x - m), 4 accumulators for ILP
            float s0 = 0.f, s1 = 0.f, s2 = 0.f, s3 = 0.f;
#pragma unroll
            for (int j = 0; j < 8; ++j) {
                s0 += __expf(x[j].x - m);
                s1 += __expf(x[j].y - m);
                s2 += __expf(x[j].z - m);
                s3 += __expf(x[j].w - m);
            }
            float s = (s0 + s1) + (s2 + s3);

            bool msk  = (lbl != IGNORE_ID);
            int  slbl = (lbl < 0) ? 0 : lbl;
            // x[slbl]: one dynamic ds_read_b32 from the swizzled row
            float xl = stf[(lane * 8 + (((slbl >> 2) & 7) ^ (lane & 7))) * 4 + (slbl & 3)];

            float lse = m + __logf(s);
            ce_sum += msk ? (lse - xl) : 0.0f;
            cnt    += msk ? 1 : 0;
            cor    += (msk && arg == lbl) ? 1 : 0;

            bool pf = (arg == PATH_ID);
            path[tok] = pf ? 1 : 0;
            uint64_t w = __ballot(pf);
            if (lane == 0) words[tile] = w;    // tile == word index
        }
        __syncthreads();   // path[], words[] complete

        // ---------------- block reductions: ce_sum, cnt, cor ----------------
        for (int d = 1; d < 64; d <<= 1) {
            ce_sum += __shfl_xor(ce_sum, d);
            cnt    += __shfl_xor(cnt, d);
            cor    += __shfl_xor(cor, d);
        }
        if (lane == 0) { wr_f[wid] = ce_sum; wr_i[wid] = cnt; wr_j[wid] = cor; }
        __syncthreads();

        if (tid == 0) {
            float ce_tot = 0.0f; int c_tot = 0, k_tot = 0;
#pragma unroll
            for (int v = 0; v < NWAVES; ++v) {
                ce_tot += wr_f[v]; c_tot += wr_i[v]; k_tot += wr_j[v];
            }
            float lm = ce_tot / (float)max(c_tot, 1);
            float t  = (k_tot == c_tot) ? 1.0f : 0.0f;
            float xq = qhalt[b];
            float bce = fmaxf(xq, 0.0f) - xq * t + log1pf(expf(-fabsf(xq)));
            part_a = lm + 0.5f * bce;
        }

        // ---------------- offs prefix: wave-0 scan over word popcounts ------
        if (wid == 0) {
            uint64_t w = (lane < NWORDS) ? words[lane] : 0ull;
            int pc = __popcll(w);
            int c = pc;
            for (int d = 1; d < 32; d <<= 1) {
                int t = __shfl_up(c, d);
                if (lane >= d) c += t;
            }
            if (lane < NWORDS) offs[lane] = c - pc;          // exclusive prefix
            if (lane == NWORDS - 1) { offs[NWORDS] = c; npath_s = c; }
        }
        __syncthreads();   // offs/npath_s/part_a visible

        // ---------------- scatter path positions + init labels --------------
        for (int i = tid; i < SEQ; i += BLK)
            lab[i] = path[i] ? (uint16_t)i : (uint16_t)0xFFFF;
        if (tid < NWORDS) {
            int o = offs[tid];
            uint64_t w = words[tid];
            int basei = tid * 64;
            while (w) {
                int k = __ffsll((unsigned long long)w) - 1;
                pos[o++] = (uint16_t)(basei + k);
                w &= (w - 1);
            }
        }
        __syncthreads();

        // ---------------- spatial penalty -----------------------------------
        const int np = npath_s;
        int sp_units = 0;
        for (int q = tid; q + 1 < np; q += BLK) {
            int i = pos[q], j = pos[q + 1];
            int dist = abs(i / GRIDW - j / GRIDW) + abs(i % GRIDW - j % GRIDW);
            if (dist > 1) sp_units += dist - 1;
        }

        // ---------------- connectivity: min-label propagation ---------------
        for (;;) {
            int local = 0;
            for (int i = tid; i < SEQ; i += BLK) {
                if (!path[i]) continue;
                int rr = i / GRIDW, cc = i % GRIDW;
                uint16_t v = lab[i];
                uint16_t nm = v;
                if (rr > 0)         { uint16_t u = lab[i - GRIDW]; nm = (u < nm) ? u : nm; }
                if (rr < GRIDW - 1) { uint16_t u = lab[i + GRIDW]; nm = (u < nm) ? u : nm; }
                if (cc > 0)         { uint16_t u = lab[i - 1];     nm = (u < nm) ? u : nm; }
                if (cc < GRIDW - 1) { uint16_t u = lab[i + 1];     nm = (u < nm) ? u : nm; }
                if (nm < v) { lab[i] = nm; local = 1; }
            }
            if (__syncthreads_count(local) == 0) break;
        }

        int comp = 0;
        for (int i = tid; i < SEQ; i += BLK)
            comp += (path[i] && lab[i] == (uint16_t)i) ? 1 : 0;

        // ---------------- reduce sp_units / comp, emit row contribution -----
        for (int d = 1; d < 64; d <<= 1) {
            sp_units += __shfl_xor(sp_units, d);
            comp     += __shfl_xor(comp, d);
        }
        if (lane == 0) { wr_i[wid] = sp_units; wr_j[wid] = comp; }
        __syncthreads();

        if (tid == 0) {
            int sp_tot = 0, comp_tot = 0;
#pragma unroll
            for (int v = 0; v < NWAVES; ++v) { sp_tot += wr_i[v]; comp_tot += wr_j[v]; }
            int conn_units = (comp_tot > 1) ? (comp_tot - 1) : 0;
            float total = part_a +
                          ((float)sp_tot * 10.0f + (float)conn_units * 5.0f) / (float)B;
            atomicAdd(out, total);
        }
        __syncthreads();   // protect shared arrays before next row reuses them
    }
}

extern "C" void kernel_launch(void* const* d_in, const int* in_sizes, int n_in,
                              void* d_out, int out_size, void* d_ws, size_t ws_size,
                              hipStream_t stream) {
    const float* logits = (const float*)d_in[0];
    const int*   labels = (const int*)d_in[1];
    const float* qhalt  = (const float*)d_in[2];
    // d_in[3] = halted, d_in[4] = steps: metrics-only in reference, unused.
    float* out = (float*)d_out;
    const int B = in_sizes[2];   // q_halt_logits length = batch

    // harness poisons d_out before every launch; we accumulate via atomicAdd,
    // so zero it on-stream first (graph-capture safe).
    hipMemsetAsync(out, 0, (size_t)out_size * sizeof(float), stream);
    const int nblk = (B + ROWS_PER_BLK - 1) / ROWS_PER_BLK;
    act_loss_kernel<<<dim3(nblk), dim3(BLK), 0, stream>>>(logits, labels, qhalt, out, B);
}